// Round 2
// baseline (1042.833 us; speedup 1.0000x reference)
//
#include <hip/hip_runtime.h>

// GroupedKAAttention on MI355X (gfx950).
// Pipeline: grouped fc1 -> grouped fc4 -> global fc1 (split-K=16, permuted W
// rows fold the stack/interleave) -> reduce+silu -> global fc4 (split-K=8) ->
// reduce+silu -> per-row dot -> softmax over batch.
// GEMMs: bf16x3 split (hi/lo) MFMA 16x16x32, fp32 accumulate; 128x128 tile,
// BK=32, 4 waves, XOR-swizzled LDS, next-tile prefetch.
// R1: intermediates (hqk, fqk, h2) stored as PRE-SPLIT hi/lo bf16 planes by
// the producing epilogue -> consuming GEMM's A path has zero conversion VALU.
// Deeper split-K on global layers -> 2 blocks/CU (was 1).

#define CB 256      // batch
#define CG 16       // groups
#define CGS 588     // group size
#define CHID 1024
#define CFEAT 2048

typedef __attribute__((ext_vector_type(8))) short bf16x8;
typedef __attribute__((ext_vector_type(4))) float f32x4;

__device__ __forceinline__ int lds_addr(int row, int kcol) {
  // 128 rows x 32 bf16 (64B) per plane; swizzle 16B slot by (row>>1)&3 so that
  // b128 frag reads (16 rows, same k-block) spread over 8 slots -> 2-way free.
  return row * 64 + ((((kcol >> 3) ^ ((row >> 1) & 3)) << 4) | ((kcol & 7) << 1));
}

__device__ __forceinline__ void split4(const float4& v, uint2& hi, uint2& lo) {
  // x = hi + lo, both bf16 (truncation split: |x-(hi+lo)| <= 2^-16 |x|)
  unsigned u0 = __float_as_uint(v.x), u1 = __float_as_uint(v.y);
  unsigned u2 = __float_as_uint(v.z), u3 = __float_as_uint(v.w);
  unsigned h0 = u0 & 0xffff0000u, h1 = u1 & 0xffff0000u;
  unsigned h2 = u2 & 0xffff0000u, h3 = u3 & 0xffff0000u;
  hi.x = (h0 >> 16) | h1;
  hi.y = (h2 >> 16) | h3;
  float r0 = v.x - __uint_as_float(h0), r1 = v.y - __uint_as_float(h1);
  float r2 = v.z - __uint_as_float(h2), r3 = v.w - __uint_as_float(h3);
  lo.x = (__float_as_uint(r0) >> 16) | (__float_as_uint(r1) & 0xffff0000u);
  lo.y = (__float_as_uint(r2) >> 16) | (__float_as_uint(r3) & 0xffff0000u);
}

__device__ __forceinline__ float silu_f(float x) {
  return x / (1.f + __expf(-x));
}

// ---------------------------------------------------------------------------
// 128x128 tile GEMM.
// GROUPED: blockIdx.z = br*16+g (branch, group). Else blockIdx.z = split-K id.
// PERMUTE: B row = ((k&2047)<<4)|(k>>11) (stack-interleave folded in).
// ASPLIT:  A input is pre-split bf16 hi/lo planes (lo at +a_plane elems);
//          requires K-range multiple of 32 (no tail) and 16B-aligned rows.
// EPI: 2 = silu -> split bf16 hi/lo planes (lo at +c_plane); 1 = silu fp32;
//      0 = raw fp32 partial (split-K), C base += z*c_sstride.
// ---------------------------------------------------------------------------
template <int GROUPED, int PERMUTE, int ASPLIT, int EPI>
__global__ __launch_bounds__(256, 2) void gemm_k(
    const void* A0v, const void* A1v, long a_plane,
    const float* __restrict__ B0, const float* __restrict__ B1,
    const float* __restrict__ bias0, const float* __restrict__ bias1,
    void* Cv, long c_plane, int K, int lda, int ldb, int ldc, int a_goff,
    long a_broff, long b_gstride, int bias_gstride, long c_broff, int c_goff,
    long c_sstride, int nksteps) {
  __shared__ __align__(16) char sm[32768];
  constexpr int A_HI = 0, A_LO = 8192, B_HI = 16384, B_LO = 24576;
  const int tid = threadIdx.x;
  const int m0 = blockIdx.x * 128, n0 = blockIdx.y * 128;

  const float* Bp;
  const float* bp = nullptr;
  const float* Af = nullptr;
  const short* Ah = nullptr;
  float* Cf = nullptr;
  short* Chi = nullptr;
  int acol = 0;
  int kbase = 0;
  if (GROUPED) {
    int z = blockIdx.z;
    int br = z >> 4, g = z & 15;
    if (ASPLIT) Ah = (const short*)(br ? A1v : A0v) + (long)br * a_broff;
    else        Af = (const float*)(br ? A1v : A0v) + (long)br * a_broff;
    Bp = (br ? B1 : B0) + (long)g * b_gstride;
    if (EPI) bp = (br ? bias1 : bias0) + (long)g * bias_gstride;
    long coff = (long)br * c_broff + (long)g * c_goff;
    if (EPI == 2) Chi = (short*)Cv + coff;
    else          Cf = (float*)Cv + coff;
    acol = g * a_goff;
  } else {
    if (ASPLIT) Ah = (const short*)A0v;
    else        Af = (const float*)A0v;
    Bp = B0;
    bp = bias0;
    if (EPI == 2) Chi = (short*)Cv;
    else          Cf = (float*)Cv + (long)blockIdx.z * c_sstride;
    kbase = (int)blockIdx.z * nksteps * 32;
  }

  float4 ga[4];        // fp32-A tile regs (ASPLIT=0): 4 rows x 4 k
  uint4 gah[2], gal[2];// presplit-A tile regs (ASPLIT=1): 2 units x 8 k
  float gb[4][4];      // B tile regs: 4 k-rows x 4 k each (one n)

  auto tload = [&](int k0) {
    if (ASPLIT) {
      #pragma unroll
      for (int i = 0; i < 2; ++i) {
        int u = tid + 256 * i, row = u >> 2, kq = u & 3;
        long eo = (long)(m0 + row) * lda + acol + k0 + kq * 8;
        gah[i] = *reinterpret_cast<const uint4*>(Ah + eo);
        gal[i] = *reinterpret_cast<const uint4*>(Ah + a_plane + eo);
      }
    } else {
      const int r = tid >> 3, c4 = (tid & 7) << 2;
      const int gk = k0 + c4;
      #pragma unroll
      for (int i = 0; i < 4; ++i) {
        if (gk < K)
          ga[i] = *reinterpret_cast<const float4*>(Af + (long)(m0 + i * 32 + r) * lda + acol + gk);
        else
          ga[i] = make_float4(0.f, 0.f, 0.f, 0.f);
      }
    }
    const int n = tid & 127, kq0 = (tid >> 7) << 2;
    #pragma unroll
    for (int i = 0; i < 4; ++i) {
      #pragma unroll
      for (int j = 0; j < 4; ++j) {
        int kk = k0 + i * 8 + kq0 + j;
        float v = 0.f;
        if (kk < K) {
          long brow = PERMUTE ? (long)(((kk & 2047) << 4) | (kk >> 11)) : (long)kk;
          v = Bp[brow * ldb + n0 + n];
        }
        gb[i][j] = v;
      }
    }
  };

  auto tstore = [&]() {
    if (ASPLIT) {
      #pragma unroll
      for (int i = 0; i < 2; ++i) {
        int u = tid + 256 * i, row = u >> 2, kq = u & 3;
        int ad = row * 64 + ((kq ^ ((row >> 1) & 3)) << 4);
        *reinterpret_cast<uint4*>(sm + A_HI + ad) = gah[i];
        *reinterpret_cast<uint4*>(sm + A_LO + ad) = gal[i];
      }
    } else {
      const int r = tid >> 3, c4 = (tid & 7) << 2;
      #pragma unroll
      for (int i = 0; i < 4; ++i) {
        uint2 h, l;
        split4(ga[i], h, l);
        int ad = lds_addr(i * 32 + r, c4);
        *reinterpret_cast<uint2*>(sm + A_HI + ad) = h;
        *reinterpret_cast<uint2*>(sm + A_LO + ad) = l;
      }
    }
    const int n = tid & 127, kq0 = (tid >> 7) << 2;
    #pragma unroll
    for (int i = 0; i < 4; ++i) {
      float4 v = make_float4(gb[i][0], gb[i][1], gb[i][2], gb[i][3]);
      uint2 h, l;
      split4(v, h, l);
      int ad = lds_addr(n, i * 8 + kq0);
      *reinterpret_cast<uint2*>(sm + B_HI + ad) = h;
      *reinterpret_cast<uint2*>(sm + B_LO + ad) = l;
    }
  };

  f32x4 acc[4][4];
  #pragma unroll
  for (int a = 0; a < 4; ++a)
    #pragma unroll
    for (int b = 0; b < 4; ++b) acc[a][b] = (f32x4){0.f, 0.f, 0.f, 0.f};

  const int lane = tid & 63, w = tid >> 6;
  const int wr = w >> 1, wc = w & 1;
  const int fr = lane & 15, kb = lane >> 4;

  tload(kbase);
  for (int s = 0; s < nksteps; ++s) {
    tstore();
    __syncthreads();
    if (s + 1 < nksteps) tload(kbase + (s + 1) * 32);  // prefetch under MFMA

    bf16x8 ah[4], al[4], bh[4], bl[4];
    #pragma unroll
    for (int f = 0; f < 4; ++f) {
      int row = wr * 64 + f * 16 + fr;
      int ad = row * 64 + ((kb ^ ((row >> 1) & 3)) << 4);
      ah[f] = *reinterpret_cast<const bf16x8*>(sm + A_HI + ad);
      al[f] = *reinterpret_cast<const bf16x8*>(sm + A_LO + ad);
      int rob = wc * 64 + f * 16 + fr;
      int bd = rob * 64 + ((kb ^ ((rob >> 1) & 3)) << 4);
      bh[f] = *reinterpret_cast<const bf16x8*>(sm + B_HI + bd);
      bl[f] = *reinterpret_cast<const bf16x8*>(sm + B_LO + bd);
    }
    #pragma unroll
    for (int im = 0; im < 4; ++im) {
      #pragma unroll
      for (int jn = 0; jn < 4; ++jn) {
        acc[im][jn] = __builtin_amdgcn_mfma_f32_16x16x32_bf16(ah[im], bh[jn], acc[im][jn], 0, 0, 0);
        acc[im][jn] = __builtin_amdgcn_mfma_f32_16x16x32_bf16(ah[im], bl[jn], acc[im][jn], 0, 0, 0);
        acc[im][jn] = __builtin_amdgcn_mfma_f32_16x16x32_bf16(al[im], bh[jn], acc[im][jn], 0, 0, 0);
      }
    }
    __syncthreads();
  }

  // Epilogue. C/D frag layout: col = lane&15, row = (lane>>4)*4 + reg  [m89]
  #pragma unroll
  for (int jn = 0; jn < 4; ++jn) {
    int col = n0 + wc * 64 + jn * 16 + fr;
    float bv = EPI ? bp[col] : 0.f;
    #pragma unroll
    for (int im = 0; im < 4; ++im) {
      int row0 = m0 + wr * 64 + im * 16 + kb * 4;
      #pragma unroll
      for (int j = 0; j < 4; ++j) {
        float x = acc[im][jn][j];
        long off = (long)(row0 + j) * ldc + col;
        if (EPI == 2) {
          float y = silu_f(x + bv);
          unsigned u = __float_as_uint(y);
          unsigned hu = u & 0xffff0000u;
          float r = y - __uint_as_float(hu);
          Chi[off] = (short)(hu >> 16);
          Chi[c_plane + off] = (short)(__float_as_uint(r) >> 16);
        } else if (EPI == 1) {
          Cf[off] = silu_f(x + bv);
        } else {
          Cf[off] = x;
        }
      }
    }
  }
}

// Sum split-K partials, add bias, silu. SPLIT=1: write bf16 hi/lo planes.
template <int SPLIT>
__global__ __launch_bounds__(256) void reduce_silu_k(
    const float* __restrict__ part, const float* __restrict__ bias,
    void* outv, long plane, long MN, int N, int S) {
  long idx = ((long)blockIdx.x * blockDim.x + threadIdx.x) * 4;
  long stride = (long)gridDim.x * blockDim.x * 4;
  for (; idx < MN; idx += stride) {
    float4 a = make_float4(0.f, 0.f, 0.f, 0.f);
    for (int s = 0; s < S; ++s) {
      float4 p = *reinterpret_cast<const float4*>(&part[(long)s * MN + idx]);
      a.x += p.x; a.y += p.y; a.z += p.z; a.w += p.w;
    }
    int col = (int)(idx & (N - 1));
    float4 b = *reinterpret_cast<const float4*>(&bias[col]);
    float o[4];
    o[0] = silu_f(a.x + b.x);
    o[1] = silu_f(a.y + b.y);
    o[2] = silu_f(a.z + b.z);
    o[3] = silu_f(a.w + b.w);
    if (SPLIT) {
      unsigned u0 = __float_as_uint(o[0]) & 0xffff0000u;
      unsigned u1 = __float_as_uint(o[1]) & 0xffff0000u;
      unsigned u2 = __float_as_uint(o[2]) & 0xffff0000u;
      unsigned u3 = __float_as_uint(o[3]) & 0xffff0000u;
      uint2 hv, lv;
      hv.x = (u0 >> 16) | u1;
      hv.y = (u2 >> 16) | u3;
      lv.x = (__float_as_uint(o[0] - __uint_as_float(u0)) >> 16) |
             (__float_as_uint(o[1] - __uint_as_float(u1)) & 0xffff0000u);
      lv.y = (__float_as_uint(o[2] - __uint_as_float(u2)) >> 16) |
             (__float_as_uint(o[3] - __uint_as_float(u3)) & 0xffff0000u);
      *reinterpret_cast<uint2*>((short*)outv + idx) = hv;
      *reinterpret_cast<uint2*>((short*)outv + plane + idx) = lv;
    } else {
      float4 ov = make_float4(o[0], o[1], o[2], o[3]);
      *reinterpret_cast<float4*>((float*)outv + idx) = ov;
    }
  }
}

// scores[b] = dot(q_out[b], k_out[b]); out2 = [512][2048], rows 0-255 q.
__global__ __launch_bounds__(256) void scores_k(const float* __restrict__ out2,
                                                float* __restrict__ scores) {
  int b = blockIdx.x;
  const float* qo = out2 + (long)b * CFEAT;
  const float* ko = out2 + (long)(b + CB) * CFEAT;
  float s = 0.f;
  for (int i = threadIdx.x * 4; i < CFEAT; i += 1024) {
    float4 a = *reinterpret_cast<const float4*>(&qo[i]);
    float4 c = *reinterpret_cast<const float4*>(&ko[i]);
    s += a.x * c.x + a.y * c.y + a.z * c.z + a.w * c.w;
  }
  #pragma unroll
  for (int o = 32; o; o >>= 1) s += __shfl_down(s, o, 64);
  __shared__ float red[4];
  if ((threadIdx.x & 63) == 0) red[threadIdx.x >> 6] = s;
  __syncthreads();
  if (threadIdx.x == 0) scores[b] = red[0] + red[1] + red[2] + red[3];
}

// softmax over the 256 batch entries (one block).
__global__ __launch_bounds__(256) void softmax_k(const float* __restrict__ scores,
                                                 float* __restrict__ out) {
  int t = threadIdx.x;
  float v = scores[t];
  float m = v;
  #pragma unroll
  for (int o = 32; o; o >>= 1) m = fmaxf(m, __shfl_xor(m, o, 64));
  __shared__ float redm[4];
  if ((t & 63) == 0) redm[t >> 6] = m;
  __syncthreads();
  m = fmaxf(fmaxf(redm[0], redm[1]), fmaxf(redm[2], redm[3]));
  float e = __expf(v - m);
  float s = e;
  #pragma unroll
  for (int o = 32; o; o >>= 1) s += __shfl_xor(s, o, 64);
  __shared__ float reds[4];
  if ((t & 63) == 0) reds[t >> 6] = s;
  __syncthreads();
  s = reds[0] + reds[1] + reds[2] + reds[3];
  out[t] = e / s;
}

extern "C" void kernel_launch(void* const* d_in, const int* in_sizes, int n_in,
                              void* d_out, int out_size, void* d_ws,
                              size_t ws_size, hipStream_t stream) {
  const float* q   = (const float*)d_in[0];
  const float* kx  = (const float*)d_in[1];
  const float* Wq1 = (const float*)d_in[2];
  const float* bq1 = (const float*)d_in[3];
  const float* Wq4 = (const float*)d_in[4];
  const float* bq4 = (const float*)d_in[5];
  const float* Wk1 = (const float*)d_in[6];
  const float* bk1 = (const float*)d_in[7];
  const float* Wk4 = (const float*)d_in[8];
  const float* bk4 = (const float*)d_in[9];
  const float* Wg1 = (const float*)d_in[10];
  const float* bg1 = (const float*)d_in[11];
  const float* Wg4 = (const float*)d_in[12];
  const float* bg4 = (const float*)d_in[13];
  float* out = (float*)d_out;
  char* ws = (char*)d_ws;

  // ws layout (bytes), time-disjoint reuse; peak = 100,663,296 B:
  //  hqk planes  [0, 16.8M)      bf16 hi+lo, 2x256x16x1024 each  (stages 1-2)
  //  fqk planes  [33.5M, 100.7M) bf16 hi+lo, 2x256x16x2048 each  (stages 2-3)
  //  part3       [0, 33.5M)      fp32 [16][512][1024]            (stage 3)
  //  h2 planes   [33.5M, 35.7M)  bf16 hi+lo, 512x1024 each       (stages 3-4)
  //  part4       [35.7M, 69.2M)  fp32 [8][512][2048]             (stage 4)
  //  out2        [69.2M, 73.4M)  fp32 [512][2048]
  //  scors       [73.4M)         fp32 [256]
  short* hqk_hi = (short*)ws;
  const long hqk_plane = 8388608;
  short* fqk_hi = (short*)(ws + 33554432);
  const long fqk_plane = 16777216;
  float* part3 = (float*)ws;
  short* h2_hi = (short*)(ws + 33554432);
  const long h2_plane = 524288;
  float* part4 = (float*)(ws + 35651584);
  float* out2  = (float*)(ws + 69206016);
  float* scors = (float*)(ws + 73400320);

  dim3 blk(256);

  // 1) grouped fc1: 16x [256x588]x[588x1024] (+bias, silu) -> hqk planes
  gemm_k<1, 0, 0, 2><<<dim3(2, 8, 32), blk, 0, stream>>>(
      q, kx, 0L, Wq1, Wk1, bq1, bk1, hqk_hi, hqk_plane,
      /*K*/ CGS, /*lda*/ CG * CGS, /*ldb*/ CHID, /*ldc*/ CG * CHID,
      /*a_goff*/ CGS, /*a_broff*/ 0L, /*b_gstride*/ (long)CGS * CHID,
      /*bias_g*/ CHID, /*c_broff*/ (long)CB * CG * CHID, /*c_goff*/ CHID, 0L,
      /*nk*/ 19);

  // 2) grouped fc4: 16x [256x1024]x[1024x2048] (+bias, silu) -> fqk planes
  gemm_k<1, 0, 1, 2><<<dim3(2, 16, 32), blk, 0, stream>>>(
      hqk_hi, hqk_hi, hqk_plane, Wq4, Wk4, bq4, bk4, fqk_hi, fqk_plane,
      /*K*/ CHID, /*lda*/ CG * CHID, /*ldb*/ CFEAT, /*ldc*/ CG * CFEAT,
      /*a_goff*/ CHID, /*a_broff*/ (long)CB * CG * CHID,
      /*b_gstride*/ (long)CHID * CFEAT, /*bias_g*/ CFEAT,
      /*c_broff*/ (long)CB * CG * CFEAT, /*c_goff*/ CFEAT, 0L, /*nk*/ 32);

  // 3) global fc1: [512x32768]x[32768x1024], split-K=16, permuted W rows
  gemm_k<0, 1, 1, 0><<<dim3(4, 8, 16), blk, 0, stream>>>(
      fqk_hi, fqk_hi, fqk_plane, Wg1, Wg1, bg1, bg1, part3, 0L,
      /*K*/ CG * CFEAT, /*lda*/ CG * CFEAT, /*ldb*/ CHID, /*ldc*/ CHID, 0, 0L,
      0L, 0, 0L, 0, /*c_sstride*/ (long)512 * CHID, /*nk*/ 64);
  reduce_silu_k<1><<<512, blk, 0, stream>>>(part3, bg1, h2_hi, h2_plane,
                                            (long)512 * CHID, CHID, 16);

  // 4) global fc4: [512x1024]x[1024x2048], split-K=8
  gemm_k<0, 0, 1, 0><<<dim3(4, 16, 8), blk, 0, stream>>>(
      h2_hi, h2_hi, h2_plane, Wg4, Wg4, bg4, bg4, part4, 0L,
      /*K*/ CHID, /*lda*/ CHID, /*ldb*/ CFEAT, /*ldc*/ CFEAT, 0, 0L, 0L, 0, 0L,
      0, /*c_sstride*/ (long)512 * CFEAT, /*nk*/ 4);
  reduce_silu_k<0><<<1024, blk, 0, stream>>>(part4, bg4, out2, 0L,
                                             (long)512 * CFEAT, CFEAT, 8);

  // 5) scores + softmax over batch
  scores_k<<<256, blk, 0, stream>>>(out2, scors);
  softmax_k<<<1, blk, 0, stream>>>(scors, out);
}

// Round 4
// 1012.068 us; speedup vs baseline: 1.0304x; 1.0304x over previous
//
#include <hip/hip_runtime.h>

// GroupedKAAttention on MI355X (gfx950).
// conv(q,k -> padded bf16 hi/lo planes) -> grouped fc1 -> grouped fc4 ->
// global fc1 (SK=16, permuted W rows fold the stack-interleave) -> reduce+silu
// -> global fc4 (SK=8) -> reduce+silu -> per-row dot -> softmax over batch.
// GEMM: bf16x3 split (hi/lo, fp32 accum) MFMA 16x16x32; 128x128 tile, BK=32,
// 4 waves, XOR-swizzled LDS, register prefetch of next tile.
// R3: spill-proofing — compile-time shapes, no lambdas, B-frags preloaded (32
// reg) + A-frags per-im (8 reg) => ~150 live VGPR < 256 cap. Activations all
// pre-split bf16 planes; weights fp32 loaded coalesced + split4 in-loop.
// Plane epilogues repack through LDS -> 16B coalesced stores.
// (R4 = R3 resubmitted verbatim; R3 bench was an infra failure.)

#define CB 256
#define CG 16
#define CGS 588
#define CHID 1024
#define CFEAT 2048

typedef __attribute__((ext_vector_type(8))) short bf16x8;
typedef __attribute__((ext_vector_type(4))) float f32x4;

__device__ __forceinline__ void split4(const float4& v, uint2& hi, uint2& lo) {
  unsigned u0 = __float_as_uint(v.x), u1 = __float_as_uint(v.y);
  unsigned u2 = __float_as_uint(v.z), u3 = __float_as_uint(v.w);
  unsigned h0 = u0 & 0xffff0000u, h1 = u1 & 0xffff0000u;
  unsigned h2 = u2 & 0xffff0000u, h3 = u3 & 0xffff0000u;
  hi.x = (h0 >> 16) | h1;
  hi.y = (h2 >> 16) | h3;
  float r0 = v.x - __uint_as_float(h0), r1 = v.y - __uint_as_float(h1);
  float r2 = v.z - __uint_as_float(h2), r3 = v.w - __uint_as_float(h3);
  lo.x = (__float_as_uint(r0) >> 16) | (__float_as_uint(r1) & 0xffff0000u);
  lo.y = (__float_as_uint(r2) >> 16) | (__float_as_uint(r3) & 0xffff0000u);
}

__device__ __forceinline__ float silu_f(float x) { return x / (1.f + __expf(-x)); }

// q,k fp32 -> bf16 hi/lo planes, K padded 588->608 with zeros.
// out: [hi: [2][256][16][608]][lo: same], plane = 4,980,736 elems.
__global__ __launch_bounds__(256) void conv_qk_k(const float* __restrict__ q,
                                                 const float* __restrict__ kx,
                                                 short* __restrict__ out) {
  const int idx = blockIdx.x * 256 + threadIdx.x;
  if (idx >= 2 * CB * CG * 152) return;
  const int kp4 = (idx % 152) * 4;
  int rest = idx / 152;
  const int g = rest & 15;
  rest >>= 4;
  const int b = rest & 255;
  const int br = rest >> 8;
  float4 v = make_float4(0.f, 0.f, 0.f, 0.f);
  if (kp4 < CGS)
    v = *reinterpret_cast<const float4*>((br ? kx : q) + (long)b * (CG * CGS) + g * CGS + kp4);
  uint2 h, l;
  split4(v, h, l);
  const long off = ((long)(br * CB + b) * CG + g) * 608 + kp4;
  *reinterpret_cast<uint2*>(out + off) = h;
  *reinterpret_cast<uint2*>(out + 4980736 + off) = l;
}

// ---------------------------------------------------------------------------
// 128x128x(BK=32) GEMM, A = pre-split bf16 planes, B = fp32 (split in-loop).
// GROUPED: z = br*16+g; else z = split-K id (kbase = z*NK*32).
// PERMUTE: B row = ((k&2047)<<4)|(k>>11). BMAX: B k-guard (pad region).
// EPI 2: silu -> bf16 hi/lo planes via LDS repack. EPI 0: raw fp32 partial.
// ---------------------------------------------------------------------------
template <int KTOT, int LDA, int LDB, int LDC, int NK, int GROUPED, int PERMUTE,
          int EPI, int BMAX>
__global__ __launch_bounds__(256, 2) void gemm_k(
    const short* __restrict__ A, long a_plane, long a_broff, int a_goff,
    const float* __restrict__ B0, const float* __restrict__ B1, long b_gstride,
    const float* __restrict__ bias0, const float* __restrict__ bias1,
    int bias_g, void* Cv, long c_plane, long c_broff, int c_goff,
    long c_sstride) {
  __shared__ __align__(16) char sm[34816];
  constexpr int A_HI = 0, A_LO = 8192, B_HI = 16384, B_LO = 24576;
  const int tid = threadIdx.x;
  const int m0 = blockIdx.x * 128, n0 = blockIdx.y * 128;
  const int z = blockIdx.z;

  const short* Ab;
  const float* Bp;
  const float* bp;
  long cbase;
  int kbase = 0;
  if (GROUPED) {
    const int br = z >> 4, g = z & 15;
    Ab = A + (long)br * a_broff + (long)g * a_goff;
    Bp = (br ? B1 : B0) + (long)g * b_gstride;
    bp = (br ? bias1 : bias0) + (long)g * bias_g;
    cbase = (long)br * c_broff + (long)g * c_goff;
  } else {
    Ab = A;
    Bp = B0;
    bp = bias0;
    cbase = (long)z * c_sstride;
    kbase = z * NK * 32;
  }

  const int arow = tid >> 2, akq = tid & 3;
  const int bn = tid & 127, bk0 = (tid >> 7) << 2;

  uint4 gah[2], gal[2];
  float gb[4][4];

#define LOAD_TILE(K0)                                                          \
  {                                                                            \
    _Pragma("unroll") for (int i = 0; i < 2; ++i) {                            \
      const long eo = (long)(m0 + arow + 64 * i) * LDA + (K0) + akq * 8;       \
      gah[i] = *reinterpret_cast<const uint4*>(Ab + eo);                       \
      gal[i] = *reinterpret_cast<const uint4*>(Ab + a_plane + eo);             \
    }                                                                          \
    _Pragma("unroll") for (int i = 0; i < 4; ++i) {                            \
      _Pragma("unroll") for (int j = 0; j < 4; ++j) {                          \
        const int kk = (K0) + i * 8 + bk0 + j;                                 \
        float v = 0.f;                                                         \
        if (BMAX == KTOT || kk < BMAX) {                                       \
          const long brow =                                                    \
              PERMUTE ? (long)(((kk & 2047) << 4) | (kk >> 11)) : (long)kk;    \
          v = Bp[brow * LDB + n0 + bn];                                        \
        }                                                                      \
        gb[i][j] = v;                                                          \
      }                                                                        \
    }                                                                          \
  }

  f32x4 acc[4][4];
  #pragma unroll
  for (int a = 0; a < 4; ++a)
    #pragma unroll
    for (int b = 0; b < 4; ++b) acc[a][b] = (f32x4){0.f, 0.f, 0.f, 0.f};

  const int lane = tid & 63, w = tid >> 6;
  const int wr = w >> 1, wc = w & 1;
  const int fr = lane & 15, kb = lane >> 4;

  LOAD_TILE(kbase)
  for (int s = 0; s < NK; ++s) {
    // regs -> LDS
    #pragma unroll
    for (int i = 0; i < 2; ++i) {
      const int row = arow + 64 * i;
      const int ad = row * 64 + ((akq ^ ((row >> 1) & 3)) << 4);
      *reinterpret_cast<uint4*>(sm + A_HI + ad) = gah[i];
      *reinterpret_cast<uint4*>(sm + A_LO + ad) = gal[i];
    }
    #pragma unroll
    for (int i = 0; i < 4; ++i) {
      float4 v = make_float4(gb[i][0], gb[i][1], gb[i][2], gb[i][3]);
      uint2 h, l;
      split4(v, h, l);
      const int kcol = i * 8 + bk0;
      const int ad = bn * 64 + (((kcol >> 3) ^ ((bn >> 1) & 3)) << 4) +
                     ((kcol & 7) << 1);
      *reinterpret_cast<uint2*>(sm + B_HI + ad) = h;
      *reinterpret_cast<uint2*>(sm + B_LO + ad) = l;
    }
    __syncthreads();
    if (s + 1 < NK) LOAD_TILE(kbase + (s + 1) * 32)  // prefetch under MFMA

    bf16x8 bh[4], bl[4];
    #pragma unroll
    for (int f = 0; f < 4; ++f) {
      const int rob = wc * 64 + f * 16 + fr;
      const int bd = rob * 64 + ((kb ^ ((rob >> 1) & 3)) << 4);
      bh[f] = *reinterpret_cast<const bf16x8*>(sm + B_HI + bd);
      bl[f] = *reinterpret_cast<const bf16x8*>(sm + B_LO + bd);
    }
    #pragma unroll
    for (int im = 0; im < 4; ++im) {
      const int row = wr * 64 + im * 16 + fr;
      const int ad = row * 64 + ((kb ^ ((row >> 1) & 3)) << 4);
      bf16x8 ah = *reinterpret_cast<const bf16x8*>(sm + A_HI + ad);
      bf16x8 al = *reinterpret_cast<const bf16x8*>(sm + A_LO + ad);
      #pragma unroll
      for (int jn = 0; jn < 4; ++jn) {
        acc[im][jn] = __builtin_amdgcn_mfma_f32_16x16x32_bf16(ah, bh[jn], acc[im][jn], 0, 0, 0);
        acc[im][jn] = __builtin_amdgcn_mfma_f32_16x16x32_bf16(ah, bl[jn], acc[im][jn], 0, 0, 0);
        acc[im][jn] = __builtin_amdgcn_mfma_f32_16x16x32_bf16(al, bh[jn], acc[im][jn], 0, 0, 0);
      }
    }
    __syncthreads();
  }
#undef LOAD_TILE

  // C/D frag layout: col = lane&15, row = (lane>>4)*4 + reg  [m89]
  if (EPI == 2) {
    #pragma unroll
    for (int jn = 0; jn < 4; ++jn) {
      const float bv = bp[n0 + wc * 64 + jn * 16 + fr];
      #pragma unroll
      for (int im = 0; im < 4; ++im)
        #pragma unroll
        for (int j = 0; j < 4; ++j)
          acc[im][jn][j] = silu_f(acc[im][jn][j] + bv);
    }
    short* smS = (short*)sm;  // tile 128 x 136 shorts (272B row: 4-way-free)
    short* Cs = (short*)Cv;
    #pragma unroll
    for (int p = 0; p < 2; ++p) {
      #pragma unroll
      for (int im = 0; im < 4; ++im)
        #pragma unroll
        for (int jn = 0; jn < 4; ++jn)
          #pragma unroll
          for (int j = 0; j < 4; ++j) {
            const int row = wr * 64 + im * 16 + kb * 4 + j;
            const int col = wc * 64 + jn * 16 + fr;
            const float y = acc[im][jn][j];
            const unsigned hu = __float_as_uint(y) & 0xffff0000u;
            const unsigned val =
                p == 0 ? (hu >> 16)
                       : (__float_as_uint(y - __uint_as_float(hu)) >> 16);
            smS[row * 136 + col] = (short)val;
          }
      __syncthreads();
      #pragma unroll
      for (int e = 0; e < 8; ++e) {
        const int S = (tid + 256 * e) * 8;
        const int row = S >> 7, col = S & 127;
        uint4 v = *reinterpret_cast<const uint4*>(smS + row * 136 + col);
        *reinterpret_cast<uint4*>(Cs + p * c_plane + cbase +
                                  (long)(m0 + row) * LDC + n0 + col) = v;
      }
      if (p == 0) __syncthreads();
    }
  } else {
    float* Cf = (float*)Cv + cbase;
    #pragma unroll
    for (int jn = 0; jn < 4; ++jn) {
      const int col = n0 + wc * 64 + jn * 16 + fr;
      #pragma unroll
      for (int im = 0; im < 4; ++im) {
        const int row0 = m0 + wr * 64 + im * 16 + kb * 4;
        #pragma unroll
        for (int j = 0; j < 4; ++j)
          Cf[(long)(row0 + j) * LDC + col] = acc[im][jn][j];
      }
    }
  }
}

// Sum split-K partials, add bias, silu. SPLIT=1: write bf16 hi/lo planes.
template <int SPLIT>
__global__ __launch_bounds__(256) void reduce_silu_k(
    const float* __restrict__ part, const float* __restrict__ bias,
    void* outv, long plane, long MN, int N, int S) {
  long idx = ((long)blockIdx.x * blockDim.x + threadIdx.x) * 4;
  if (idx >= MN) return;
  float4 a = make_float4(0.f, 0.f, 0.f, 0.f);
  for (int s = 0; s < S; ++s) {
    float4 p = *reinterpret_cast<const float4*>(&part[(long)s * MN + idx]);
    a.x += p.x; a.y += p.y; a.z += p.z; a.w += p.w;
  }
  const int col = (int)(idx & (N - 1));
  float4 b = *reinterpret_cast<const float4*>(&bias[col]);
  float o0 = silu_f(a.x + b.x), o1 = silu_f(a.y + b.y);
  float o2 = silu_f(a.z + b.z), o3 = silu_f(a.w + b.w);
  if (SPLIT) {
    float4 ov = make_float4(o0, o1, o2, o3);
    uint2 hv, lv;
    split4(ov, hv, lv);
    *reinterpret_cast<uint2*>((short*)outv + idx) = hv;
    *reinterpret_cast<uint2*>((short*)outv + plane + idx) = lv;
  } else {
    *reinterpret_cast<float4*>((float*)outv + idx) = make_float4(o0, o1, o2, o3);
  }
}

// scores[b] = dot(q_out[b], k_out[b]); out2 = [512][2048], rows 0-255 = q.
__global__ __launch_bounds__(256) void scores_k(const float* __restrict__ out2,
                                                float* __restrict__ scores) {
  int b = blockIdx.x;
  const float* qo = out2 + (long)b * CFEAT;
  const float* ko = out2 + (long)(b + CB) * CFEAT;
  float s = 0.f;
  for (int i = threadIdx.x * 4; i < CFEAT; i += 1024) {
    float4 a = *reinterpret_cast<const float4*>(&qo[i]);
    float4 c = *reinterpret_cast<const float4*>(&ko[i]);
    s += a.x * c.x + a.y * c.y + a.z * c.z + a.w * c.w;
  }
  #pragma unroll
  for (int o = 32; o; o >>= 1) s += __shfl_down(s, o, 64);
  __shared__ float red[4];
  if ((threadIdx.x & 63) == 0) red[threadIdx.x >> 6] = s;
  __syncthreads();
  if (threadIdx.x == 0) scores[b] = red[0] + red[1] + red[2] + red[3];
}

__global__ __launch_bounds__(256) void softmax_k(const float* __restrict__ scores,
                                                 float* __restrict__ out) {
  int t = threadIdx.x;
  float v = scores[t];
  float m = v;
  #pragma unroll
  for (int o = 32; o; o >>= 1) m = fmaxf(m, __shfl_xor(m, o, 64));
  __shared__ float redm[4];
  if ((t & 63) == 0) redm[t >> 6] = m;
  __syncthreads();
  m = fmaxf(fmaxf(redm[0], redm[1]), fmaxf(redm[2], redm[3]));
  float e = __expf(v - m);
  float s = e;
  #pragma unroll
  for (int o = 32; o; o >>= 1) s += __shfl_xor(s, o, 64);
  __shared__ float reds[4];
  if ((t & 63) == 0) reds[t >> 6] = s;
  __syncthreads();
  s = reds[0] + reds[1] + reds[2] + reds[3];
  out[t] = e / s;
}

extern "C" void kernel_launch(void* const* d_in, const int* in_sizes, int n_in,
                              void* d_out, int out_size, void* d_ws,
                              size_t ws_size, hipStream_t stream) {
  const float* q   = (const float*)d_in[0];
  const float* kx  = (const float*)d_in[1];
  const float* Wq1 = (const float*)d_in[2];
  const float* bq1 = (const float*)d_in[3];
  const float* Wq4 = (const float*)d_in[4];
  const float* bq4 = (const float*)d_in[5];
  const float* Wk1 = (const float*)d_in[6];
  const float* bk1 = (const float*)d_in[7];
  const float* Wk4 = (const float*)d_in[8];
  const float* bk4 = (const float*)d_in[9];
  const float* Wg1 = (const float*)d_in[10];
  const float* bg1 = (const float*)d_in[11];
  const float* Wg4 = (const float*)d_in[12];
  const float* bg4 = (const float*)d_in[13];
  float* out = (float*)d_out;
  char* ws = (char*)d_ws;

  // ws (time-disjoint reuse, peak exactly 100,663,296 B == proven R1 bound):
  //  qkpad  [0, 19.92M)        bf16 planes [2][256][16][608]   conv -> s1
  //  hqk    [67.1M, 100.66M)   bf16 planes [2][256][16][1024]  s1 -> s2
  //  fqk    [0, 67.1M)         bf16 planes [2][256][16][2048]  s2 -> s3
  //  part3  [67.1M, 100.66M)   fp32 [16][512][1024]            s3 -> r3
  //  h2     [0, 4.19M)         bf16 planes [512][1024]         r3 -> s4
  //  part4  [67.1M, 100.66M)   fp32 [8][512][2048]             s4 -> r4
  //  out2   [4.19M, 8.39M)     fp32 [512][2048]                r4 -> scores
  //  scors  [8.39M)            fp32 [256]
  short* qkpad = (short*)ws;
  short* fqk   = (short*)ws;
  short* hqk   = (short*)(ws + 67108864);
  float* part3 = (float*)(ws + 67108864);
  short* h2    = (short*)ws;
  float* part4 = (float*)(ws + 67108864);
  float* out2  = (float*)(ws + 4194304);
  float* scors = (float*)(ws + 8388608);

  dim3 blk(256);

  // 0) q,k -> padded bf16 planes
  conv_qk_k<<<4864, blk, 0, stream>>>(q, kx, qkpad);

  // 1) grouped fc1: 16x [256x608(pad)]x[588x1024] +bias,silu -> hqk planes
  gemm_k<608, 9728, CHID, CG * CHID, 19, 1, 0, 2, 588>
      <<<dim3(2, 8, 32), blk, 0, stream>>>(
          qkpad, 4980736L, 2490368L, 608, Wq1, Wk1, (long)CGS * CHID, bq1, bk1,
          CHID, hqk, 8388608L, 4194304L, CHID, 0L);

  // 2) grouped fc4: 16x [256x1024]x[1024x2048] +bias,silu -> fqk planes
  gemm_k<CHID, CG * CHID, CFEAT, CG * CFEAT, 32, 1, 0, 2, CHID>
      <<<dim3(2, 16, 32), blk, 0, stream>>>(
          hqk, 8388608L, 4194304L, CHID, Wq4, Wk4, (long)CHID * CFEAT, bq4, bk4,
          CFEAT, fqk, 16777216L, 8388608L, CFEAT, 0L);

  // 3) global fc1: [512x32768]x[32768x1024], SK=16, permuted W rows
  gemm_k<CG * CFEAT, CG * CFEAT, CHID, CHID, 64, 0, 1, 0, CG * CFEAT>
      <<<dim3(4, 8, 16), blk, 0, stream>>>(
          fqk, 16777216L, 0L, 0, Wg1, Wg1, 0L, bg1, bg1, 0, part3, 0L, 0L, 0,
          (long)512 * CHID);
  reduce_silu_k<1><<<512, blk, 0, stream>>>(part3, bg1, h2, 524288L,
                                            (long)512 * CHID, CHID, 16);

  // 4) global fc4: [512x1024]x[1024x2048], SK=8
  gemm_k<CHID, CHID, CFEAT, CFEAT, 4, 0, 0, 0, CHID>
      <<<dim3(4, 16, 8), blk, 0, stream>>>(
          h2, 524288L, 0L, 0, Wg4, Wg4, 0L, bg4, bg4, 0, part4, 0L, 0L, 0,
          (long)512 * CFEAT);
  reduce_silu_k<0><<<1024, blk, 0, stream>>>(part4, bg4, out2, 0L,
                                             (long)512 * CFEAT, CFEAT, 8);

  // 5) scores + softmax over batch
  scores_k<<<256, blk, 0, stream>>>(out2, scors);
  softmax_k<<<1, blk, 0, stream>>>(scors, out);
}